// Round 7
// baseline (1177.215 us; speedup 1.0000x reference)
//
#include <hip/hip_runtime.h>
#include <hip/hip_bf16.h>

// Pipeline (N=50000, E=1.6M, D=16, NK=2):
//   bhist: LDS-private bucket histogram (bucket = dst>>9)
//   bscan: column-sum + scan 128 buckets -> bbase/bcur(padded)/off[N]=E
//   partA: bucket-partition edges into staging (LDS-staged, coalesced writes)
//   partB: per-bucket node sort -> packed Rec stream (src|dl<<24, k0, k1) + off
//   conv1+mlp1: per-64-node block, edge-parallel, LDS ds_add accumulate,
//               then shfl-MLP + l2norm from LDS -> h1[N,32]
//   conv2:      same structure -> h2[N,64]
//   mlp2:       out = l2norm(relu(h2@W2a+b2a)@W2b + b2b)  [reg-tiled GEMM]

#define EPSV 1e-12f
#define CHUNK 2048      // edges per partA block
#define NBMAX 128       // bucket slots (nbuck = ceil(N/512) = 98 <= 128)
#define BNODES 512      // nodes per partition bucket (dst >> 9)
#define BCPAD 16        // bcur padding stride (ints) -> 1 cache line per bucket

struct __align__(4) Rec { int sd; float k0, k1; };  // sd = src | (dst&63)<<24

// ---- detect whether edge_index buffer is int64 (odd int32 words all zero) ----
__global__ void detect_i64_kernel(const int* ei, int* flag) {
    int lane = threadIdx.x;
    int nonzero = 0;
    for (int i = lane; i < 1024; i += 64) {
        if (ei[2 * i + 1] != 0) nonzero = 1;
    }
    unsigned long long b = __ballot(nonzero);
    if (lane == 0) *flag = (b == 0ull) ? 1 : 0;   // 1 => int64 layout
}

__device__ __forceinline__ void load_edge(const int* ei, int e, int E, int flag,
                                          int& src, int& dst) {
    if (flag) {            // int64 storage: low words at even int32 indices
        src = ei[2 * e];
        dst = ei[2 * E + 2 * e];
    } else {               // int32 storage
        src = ei[e];
        dst = ei[E + e];
    }
}

// ---- bucket histogram: LDS-privatized, one cntmat row per block ----
__global__ __launch_bounds__(256) void bhist_kernel(
        const int* __restrict__ ei, const int* __restrict__ flagp,
        int* __restrict__ cntmat, int E) {
    __shared__ int l[NBMAX];
    if (threadIdx.x < NBMAX) l[threadIdx.x] = 0;
    __syncthreads();
    int flag = *flagp;
    int stride = gridDim.x * 256;
    for (int e = blockIdx.x * 256 + threadIdx.x; e < E; e += stride) {
        int dst = flag ? ei[2 * E + 2 * e] : ei[E + e];
        atomicAdd(&l[dst >> 9], 1);
    }
    __syncthreads();
    if (threadIdx.x < NBMAX) cntmat[blockIdx.x * NBMAX + threadIdx.x] = l[threadIdx.x];
}

// ---- column-sum cntmat + exclusive scan of bucket counts ----
__global__ void bscan_kernel(const int* __restrict__ cntmat,
                             int* __restrict__ bbase, int* __restrict__ bcur,
                             int* __restrict__ off,
                             int nbuck, int E, int nrows, int N) {
    __shared__ int s[NBMAX];
    int t = threadIdx.x;            // blockDim = NBMAX
    int c = 0;
    for (int i = 0; i < nrows; ++i) c += cntmat[i * NBMAX + t];
    s[t] = c;
    __syncthreads();
    for (int d = 1; d < NBMAX; d <<= 1) {
        int v = (t >= d) ? s[t - d] : 0;
        __syncthreads();
        s[t] += v;
        __syncthreads();
    }
    int excl = s[t] - c;
    if (t < nbuck) { bbase[t] = excl; bcur[t * BCPAD] = excl; }
    if (t == 0) { bbase[nbuck] = E; off[N] = E; }
}

// ---- partA: bucket-partition edges by dst>>9, LDS-staged ----
__global__ __launch_bounds__(256) void partA_kernel(
        const float* __restrict__ K, const int* __restrict__ ei,
        const int* __restrict__ flagp, int* __restrict__ bcur,
        int4* __restrict__ staging, int E) {
    __shared__ int cnt[NBMAX];
    __shared__ int bexc[NBMAX];
    __shared__ int gbase[NBMAX];
    __shared__ int scanbuf[NBMAX];
    __shared__ int4 stage[CHUNK];     // 32 KB

    int flag = *flagp;
    int e0 = blockIdx.x * CHUNK;
    int tot = min(CHUNK, E - e0);

    for (int b = threadIdx.x; b < NBMAX; b += 256) cnt[b] = 0;
    __syncthreads();

    int  myslot[CHUNK / 256];
    int  mybk[CHUNK / 256];
    int4 myrec[CHUNK / 256];
#pragma unroll
    for (int it = 0; it < CHUNK / 256; ++it) {
        int e = e0 + it * 256 + threadIdx.x;
        mybk[it] = -1;
        if (e < E) {
            int src, dst;
            load_edge(ei, e, E, flag, src, dst);
            int bk = dst >> 9;
            mybk[it] = bk;
            myrec[it] = make_int4(src, __float_as_int(K[e]),
                                  __float_as_int(K[E + e]), dst);
            myslot[it] = atomicAdd(&cnt[bk], 1);
        }
    }
    __syncthreads();

    if (threadIdx.x < NBMAX) scanbuf[threadIdx.x] = cnt[threadIdx.x];
    __syncthreads();
    for (int d = 1; d < NBMAX; d <<= 1) {
        int v = 0;
        if (threadIdx.x < NBMAX && threadIdx.x >= d) v = scanbuf[threadIdx.x - d];
        __syncthreads();
        if (threadIdx.x < NBMAX) scanbuf[threadIdx.x] += v;
        __syncthreads();
    }
    if (threadIdx.x < NBMAX) {
        int c = cnt[threadIdx.x];
        bexc[threadIdx.x] = scanbuf[threadIdx.x] - c;
        gbase[threadIdx.x] = c ? atomicAdd(&bcur[threadIdx.x * BCPAD], c) : 0;
    }
    __syncthreads();

#pragma unroll
    for (int it = 0; it < CHUNK / 256; ++it) {
        if (mybk[it] >= 0) stage[bexc[mybk[it]] + myslot[it]] = myrec[it];
    }
    __syncthreads();

    for (int i = threadIdx.x; i < tot; i += 256) {
        int4 r = stage[i];
        int bk = r.w >> 9;
        staging[gbase[bk] + (i - bexc[bk])] = r;
    }
}

// ---- partB: per-bucket node sort; emits packed Rec + off ----
__global__ __launch_bounds__(1024) void partB_kernel(
        const int4* __restrict__ staging, const int* __restrict__ bbase,
        int* __restrict__ off, Rec* __restrict__ recs, int N) {
    __shared__ int lcnt[BNODES];
    __shared__ int lscan[BNODES];

    int b = blockIdx.x;
    int nodeBase = b << 9;
    int s0 = bbase[b];
    int s1 = bbase[b + 1];
    int t = threadIdx.x;

    if (t < BNODES) lcnt[t] = 0;
    __syncthreads();

    for (int i = s0 + t; i < s1; i += 1024)
        atomicAdd(&lcnt[staging[i].w - nodeBase], 1);
    __syncthreads();

    if (t < BNODES) lscan[t] = lcnt[t];
    __syncthreads();
    for (int d = 1; d < BNODES; d <<= 1) {
        int v = 0;
        if (t < BNODES && t >= d) v = lscan[t - d];
        __syncthreads();
        if (t < BNODES) lscan[t] += v;
        __syncthreads();
    }
    if (t < BNODES) {
        int node = nodeBase + t;
        if (node < N) {
            int c = lcnt[t];
            int o = s0 + lscan[t] - c;   // exclusive offset, absolute
            off[node] = o;
            lcnt[t] = o;                 // becomes the cursor
        }
    }
    __syncthreads();

    for (int i = s0 + t; i < s1; i += 1024) {
        int4 r = staging[i];
        int pos = atomicAdd(&lcnt[r.w - nodeBase], 1);
        Rec w;
        w.sd = r.x | ((r.w & 63) << 24);
        w.k0 = __int_as_float(r.y);
        w.k1 = __int_as_float(r.z);
        recs[pos] = w;
    }
}

// ---- conv1 + MLP1: 64 nodes/block, edge-parallel, LDS accumulate ----
__global__ __launch_bounds__(512) void conv1_mlp1_kernel(
        const float* __restrict__ x, const Rec* __restrict__ recs,
        const int* __restrict__ off, const float* __restrict__ W1,
        const float* __restrict__ b1, float* __restrict__ h1, int N) {
    __shared__ float w[1024];
    __shared__ float bsh[32];
    __shared__ float buf[64 * 33];   // padded: bank = (dl + lane) & 31
    int tid = threadIdx.x;
    for (int i = tid; i < 1024; i += 512) w[i] = W1[i];
    if (tid < 32) bsh[tid] = b1[tid];
    for (int i = tid; i < 64 * 33; i += 512) buf[i] = 0.f;
    __syncthreads();

    int n0 = blockIdx.x * 64;
    int nEnd = min(n0 + 64, N);
    int eBeg = off[n0], eEnd = off[nEnd];
    int hw = tid >> 5, lane = tid & 31;
    int c = lane & 15;
    bool hi = lane >= 16;

    int i = eBeg + hw;
    for (; i + 48 < eEnd; i += 64) {
        Rec r0 = recs[i], r1 = recs[i + 16], r2 = recs[i + 32], r3 = recs[i + 48];
        float v0 = x[(r0.sd & 0xFFFFFF) * 16 + c];
        float v1 = x[(r1.sd & 0xFFFFFF) * 16 + c];
        float v2 = x[(r2.sd & 0xFFFFFF) * 16 + c];
        float v3 = x[(r3.sd & 0xFFFFFF) * 16 + c];
        atomicAdd(&buf[((unsigned)r0.sd >> 24) * 33 + lane], (hi ? r0.k1 : r0.k0) * v0);
        atomicAdd(&buf[((unsigned)r1.sd >> 24) * 33 + lane], (hi ? r1.k1 : r1.k0) * v1);
        atomicAdd(&buf[((unsigned)r2.sd >> 24) * 33 + lane], (hi ? r2.k1 : r2.k0) * v2);
        atomicAdd(&buf[((unsigned)r3.sd >> 24) * 33 + lane], (hi ? r3.k1 : r3.k0) * v3);
    }
    for (; i < eEnd; i += 16) {
        Rec r = recs[i];
        float v = x[(r.sd & 0xFFFFFF) * 16 + c];
        atomicAdd(&buf[((unsigned)r.sd >> 24) * 33 + lane], (hi ? r.k1 : r.k0) * v);
    }
    __syncthreads();

    // MLP1 + l2norm: half-wave per node, row in LDS (lane = k*16+ch matches layout)
    for (int nn = hw; nn < 64; nn += 16) {
        int node = n0 + nn;
        if (node >= N) break;
        float acc = buf[nn * 33 + lane];
        float o = bsh[lane];
#pragma unroll
        for (int q = 0; q < 32; q++) o += __shfl(acc, q, 32) * w[q * 32 + lane];
        o = fmaxf(o, 0.f);
        float ss = o * o;
#pragma unroll
        for (int m = 16; m >= 1; m >>= 1) ss += __shfl_xor(ss, m, 32);
        h1[node * 32 + lane] = o / fmaxf(sqrtf(ss), EPSV);
    }
}

// ---- conv2: 64 nodes/block, edge-parallel, LDS accumulate, 64 out ch ----
__global__ __launch_bounds__(512) void conv2_kernel(
        const float* __restrict__ h1, const Rec* __restrict__ recs,
        const int* __restrict__ off, float* __restrict__ h2, int N) {
    __shared__ float buf[64 * 68];   // padded: bank = (4*dl + ch) & 31
    int tid = threadIdx.x;
    for (int i = tid; i < 64 * 68; i += 512) buf[i] = 0.f;
    __syncthreads();

    int n0 = blockIdx.x * 64;
    int nEnd = min(n0 + 64, N);
    int eBeg = off[n0], eEnd = off[nEnd];
    int hw = tid >> 5, lane = tid & 31;

    int i = eBeg + hw;
    for (; i + 48 < eEnd; i += 64) {
        Rec r0 = recs[i], r1 = recs[i + 16], r2 = recs[i + 32], r3 = recs[i + 48];
        float v0 = h1[(r0.sd & 0xFFFFFF) * 32 + lane];
        float v1 = h1[(r1.sd & 0xFFFFFF) * 32 + lane];
        float v2 = h1[(r2.sd & 0xFFFFFF) * 32 + lane];
        float v3 = h1[(r3.sd & 0xFFFFFF) * 32 + lane];
        int d0 = (unsigned)r0.sd >> 24, d1 = (unsigned)r1.sd >> 24;
        int d2 = (unsigned)r2.sd >> 24, d3 = (unsigned)r3.sd >> 24;
        atomicAdd(&buf[d0 * 68 + lane],      r0.k0 * v0);
        atomicAdd(&buf[d0 * 68 + 32 + lane], r0.k1 * v0);
        atomicAdd(&buf[d1 * 68 + lane],      r1.k0 * v1);
        atomicAdd(&buf[d1 * 68 + 32 + lane], r1.k1 * v1);
        atomicAdd(&buf[d2 * 68 + lane],      r2.k0 * v2);
        atomicAdd(&buf[d2 * 68 + 32 + lane], r2.k1 * v2);
        atomicAdd(&buf[d3 * 68 + lane],      r3.k0 * v3);
        atomicAdd(&buf[d3 * 68 + 32 + lane], r3.k1 * v3);
    }
    for (; i < eEnd; i += 16) {
        Rec r = recs[i];
        float v = h1[(r.sd & 0xFFFFFF) * 32 + lane];
        int d = (unsigned)r.sd >> 24;
        atomicAdd(&buf[d * 68 + lane],      r.k0 * v);
        atomicAdd(&buf[d * 68 + 32 + lane], r.k1 * v);
    }
    __syncthreads();

    for (int idx = tid; idx < 64 * 64; idx += 512) {
        int nn = idx >> 6, ch = idx & 63;
        int node = n0 + nn;
        if (node < N) h2[node * 64 + ch] = buf[nn * 68 + ch];
    }
}

// ---- MLP2 register-tiled: 64 nodes/block, 256 threads ----
__global__ __launch_bounds__(256) void mlp2_kernel(
        const float* __restrict__ h2,
        const float* __restrict__ W2a,
        const float* __restrict__ b2a,
        const float* __restrict__ W2b,
        const float* __restrict__ b2b,
        float* __restrict__ out, int N) {
    __shared__ float xs[64 * 68];
    __shared__ float hs[128 * 68];

    int tid = threadIdx.x;
    int n0 = blockIdx.x * 64;

#pragma unroll
    for (int it = 0; it < 4; ++it) {
        int idx = tid + it * 256;
        int n = idx >> 4;
        int c4 = (idx & 15) * 4;
        float4 v = make_float4(0.f, 0.f, 0.f, 0.f);
        if (n0 + n < N) v = *(const float4*)&h2[(size_t)(n0 + n) * 64 + c4];
        xs[(c4 + 0) * 68 + n] = v.x;
        xs[(c4 + 1) * 68 + n] = v.y;
        xs[(c4 + 2) * 68 + n] = v.z;
        xs[(c4 + 3) * 68 + n] = v.w;
    }
    __syncthreads();

    int rg = tid >> 4;
    int cg = tid & 15;

    float acc[4][8];
#pragma unroll
    for (int j = 0; j < 4; j++)
#pragma unroll
        for (int i = 0; i < 8; i++) acc[j][i] = 0.0f;

    for (int k = 0; k < 64; ++k) {
        float4 xv = *(const float4*)&xs[k * 68 + rg * 4];
        float4 w0 = *(const float4*)&W2a[k * 128 + cg * 8];
        float4 w1 = *(const float4*)&W2a[k * 128 + cg * 8 + 4];
        float wv[8] = {w0.x, w0.y, w0.z, w0.w, w1.x, w1.y, w1.z, w1.w};
        float xr[4] = {xv.x, xv.y, xv.z, xv.w};
#pragma unroll
        for (int j = 0; j < 4; j++)
#pragma unroll
            for (int i = 0; i < 8; i++) acc[j][i] += xr[j] * wv[i];
    }

#pragma unroll
    for (int i = 0; i < 8; i++) {
        float bi = b2a[cg * 8 + i];
#pragma unroll
        for (int j = 0; j < 4; j++) {
            float hv = fmaxf(acc[j][i] + bi, 0.0f);
            hs[(cg * 8 + i) * 68 + rg * 4 + j] = hv;
        }
    }
    __syncthreads();

    float a2[4][4];
#pragma unroll
    for (int j = 0; j < 4; j++)
#pragma unroll
        for (int i = 0; i < 4; i++) a2[j][i] = 0.0f;

    for (int k = 0; k < 128; ++k) {
        float4 hv = *(const float4*)&hs[k * 68 + rg * 4];
        float4 w = *(const float4*)&W2b[k * 64 + cg * 4];
        float wv[4] = {w.x, w.y, w.z, w.w};
        float hr[4] = {hv.x, hv.y, hv.z, hv.w};
#pragma unroll
        for (int j = 0; j < 4; j++)
#pragma unroll
            for (int i = 0; i < 4; i++) a2[j][i] += hr[j] * wv[i];
    }

#pragma unroll
    for (int i = 0; i < 4; i++) {
        float bi = b2b[cg * 4 + i];
#pragma unroll
        for (int j = 0; j < 4; j++) a2[j][i] += bi;
    }

#pragma unroll
    for (int j = 0; j < 4; j++) {
        float ss = a2[j][0] * a2[j][0] + a2[j][1] * a2[j][1] +
                   a2[j][2] * a2[j][2] + a2[j][3] * a2[j][3];
#pragma unroll
        for (int m = 1; m < 16; m <<= 1) ss += __shfl_xor(ss, m, 64);
        float invn = 1.0f / fmaxf(sqrtf(ss), EPSV);
        int n = n0 + rg * 4 + j;
        if (n < N) {
            float4 o = make_float4(a2[j][0] * invn, a2[j][1] * invn,
                                   a2[j][2] * invn, a2[j][3] * invn);
            *(float4*)&out[(size_t)n * 64 + cg * 4] = o;
        }
    }
}

extern "C" void kernel_launch(void* const* d_in, const int* in_sizes, int n_in,
                              void* d_out, int out_size, void* d_ws, size_t ws_size,
                              hipStream_t stream) {
    const float* x   = (const float*)d_in[0];
    const float* K   = (const float*)d_in[1];
    const int*   ei  = (const int*)d_in[2];
    const float* W1  = (const float*)d_in[3];
    const float* b1  = (const float*)d_in[4];
    const float* W2a = (const float*)d_in[5];
    const float* b2a = (const float*)d_in[6];
    const float* W2b = (const float*)d_in[7];
    const float* b2b = (const float*)d_in[8];
    float* out = (float*)d_out;

    const int D  = 16;
    const int NK = 2;
    const int N  = in_sizes[0] / D;        // 50000
    const int E  = in_sizes[1] / NK;       // 1600000
    const int nbuck = (N + 511) >> 9;      // 98 <= NBMAX
    const int nsub  = (N + 63) >> 6;       // 782 conv blocks
    const int HROWS = 256;                 // bhist blocks

    // workspace layout:
    //   region0: staging int4 E*16 (overlaid after partB by h1[N*32]|h2[N*64])
    //   then: recs[E] (12B) | off[N+1] | cntmat[HROWS*NBMAX] |
    //         bbase[NBMAX+1] | bcur[NBMAX*BCPAD] | flag[1]
    size_t region0 = (size_t)E * 16;
    size_t hbytes  = (size_t)N * 96 * 4;
    if (hbytes > region0) region0 = hbytes;

    float* h1     = (float*)d_ws;
    float* h2     = h1 + (size_t)N * 32;
    int4* staging = (int4*)d_ws;
    Rec* recs     = (Rec*)((char*)d_ws + region0);
    int* off      = (int*)((char*)recs + (size_t)E * sizeof(Rec));
    int* cntmat   = off + (N + 1);
    int* bbase    = cntmat + HROWS * NBMAX;
    int* bcur     = bbase + NBMAX + 1;
    int* flag     = bcur + NBMAX * BCPAD;

    detect_i64_kernel<<<1, 64, 0, stream>>>(ei, flag);
    bhist_kernel<<<HROWS, 256, 0, stream>>>(ei, flag, cntmat, E);
    bscan_kernel<<<1, NBMAX, 0, stream>>>(cntmat, bbase, bcur, off,
                                          nbuck, E, HROWS, N);

    int ablocks = (E + CHUNK - 1) / CHUNK;
    partA_kernel<<<ablocks, 256, 0, stream>>>(K, ei, flag, bcur, staging, E);
    partB_kernel<<<nbuck, 1024, 0, stream>>>(staging, bbase, off, recs, N);

    conv1_mlp1_kernel<<<nsub, 512, 0, stream>>>(x, recs, off, W1, b1, h1, N);
    conv2_kernel<<<nsub, 512, 0, stream>>>(h1, recs, off, h2, N);
    mlp2_kernel<<<(N + 63) / 64, 256, 0, stream>>>(h2, W2a, b2a, W2b, b2b,
                                                   out, N);
}

// Round 8
// 223.700 us; speedup vs baseline: 5.2625x; 5.2625x over previous
//
#include <hip/hip_runtime.h>
#include <hip/hip_bf16.h>

// Pipeline (N=50000, E=1.6M, D=16, NK=2):
//   bhist: LDS-private bucket histogram (bucket = dst>>9)
//   bscan: column-sum + scan buckets -> bbase/bcur(padded)/off[N]=E sentinel
//   partA: bucket-partition edges into staging (LDS-staged, coalesced writes)
//   partB: per-bucket node sort -> srcS/kS dst-sorted + off (L2-local writes)
//   conv1+mlp1: wave-pair structure: 16-lane group per edge, dual k-acc,
//               combine, then half-wave shfl MLP + l2norm -> h1[N,32]
//   conv2:      wave per node, 8-lane group per edge, float4 row gather
//   mlp2:       out = l2norm(relu(h2@W2a+b2a)@W2b + b2b)  [reg-tiled GEMM]
//
// NOTE (round-7 post-mortem): NEVER use atomicAdd on __shared__ float in hot
// loops on gfx950 — it serializes catastrophically (678us vs 59us gather).

#define EPSV 1e-12f
#define CHUNK 2048      // edges per partA block
#define NBMAX 128       // bucket slots (nbuck = ceil(N/512) = 98 <= 128)
#define BNODES 512      // nodes per partition bucket (dst >> 9)
#define BCPAD 16        // bcur padding stride (ints) -> 1 cache line per bucket

// ---- detect whether edge_index buffer is int64 (odd int32 words all zero) ----
__global__ void detect_i64_kernel(const int* ei, int* flag) {
    int lane = threadIdx.x;
    int nonzero = 0;
    for (int i = lane; i < 1024; i += 64) {
        if (ei[2 * i + 1] != 0) nonzero = 1;
    }
    unsigned long long b = __ballot(nonzero);
    if (lane == 0) *flag = (b == 0ull) ? 1 : 0;   // 1 => int64 layout
}

__device__ __forceinline__ void load_edge(const int* ei, int e, int E, int flag,
                                          int& src, int& dst) {
    if (flag) {            // int64 storage: low words at even int32 indices
        src = ei[2 * e];
        dst = ei[2 * E + 2 * e];
    } else {               // int32 storage
        src = ei[e];
        dst = ei[E + e];
    }
}

// ---- bucket histogram: LDS-privatized, one cntmat row per block ----
__global__ __launch_bounds__(256) void bhist_kernel(
        const int* __restrict__ ei, const int* __restrict__ flagp,
        int* __restrict__ cntmat, int E) {
    __shared__ int l[NBMAX];
    if (threadIdx.x < NBMAX) l[threadIdx.x] = 0;
    __syncthreads();
    int flag = *flagp;
    int stride = gridDim.x * 256;
    for (int e = blockIdx.x * 256 + threadIdx.x; e < E; e += stride) {
        int dst = flag ? ei[2 * E + 2 * e] : ei[E + e];
        atomicAdd(&l[dst >> 9], 1);
    }
    __syncthreads();
    if (threadIdx.x < NBMAX) cntmat[blockIdx.x * NBMAX + threadIdx.x] = l[threadIdx.x];
}

// ---- column-sum cntmat + exclusive scan of bucket counts ----
__global__ void bscan_kernel(const int* __restrict__ cntmat,
                             int* __restrict__ bbase, int* __restrict__ bcur,
                             int* __restrict__ off,
                             int nbuck, int E, int nrows, int N) {
    __shared__ int s[NBMAX];
    int t = threadIdx.x;            // blockDim = NBMAX
    int c = 0;
    for (int i = 0; i < nrows; ++i) c += cntmat[i * NBMAX + t];
    s[t] = c;
    __syncthreads();
    for (int d = 1; d < NBMAX; d <<= 1) {
        int v = (t >= d) ? s[t - d] : 0;
        __syncthreads();
        s[t] += v;
        __syncthreads();
    }
    int excl = s[t] - c;
    if (t < nbuck) { bbase[t] = excl; bcur[t * BCPAD] = excl; }
    if (t == 0) { bbase[nbuck] = E; off[N] = E; }
}

// ---- partA: bucket-partition edges by dst>>9, LDS-staged ----
__global__ __launch_bounds__(256) void partA_kernel(
        const float* __restrict__ K, const int* __restrict__ ei,
        const int* __restrict__ flagp, int* __restrict__ bcur,
        int4* __restrict__ staging, int E) {
    __shared__ int cnt[NBMAX];
    __shared__ int bexc[NBMAX];
    __shared__ int gbase[NBMAX];
    __shared__ int scanbuf[NBMAX];
    __shared__ int4 stage[CHUNK];     // 32 KB

    int flag = *flagp;
    int e0 = blockIdx.x * CHUNK;
    int tot = min(CHUNK, E - e0);

    for (int b = threadIdx.x; b < NBMAX; b += 256) cnt[b] = 0;
    __syncthreads();

    int  myslot[CHUNK / 256];
    int  mybk[CHUNK / 256];
    int4 myrec[CHUNK / 256];
#pragma unroll
    for (int it = 0; it < CHUNK / 256; ++it) {
        int e = e0 + it * 256 + threadIdx.x;
        mybk[it] = -1;
        if (e < E) {
            int src, dst;
            load_edge(ei, e, E, flag, src, dst);
            int bk = dst >> 9;
            mybk[it] = bk;
            myrec[it] = make_int4(src, __float_as_int(K[e]),
                                  __float_as_int(K[E + e]), dst);
            myslot[it] = atomicAdd(&cnt[bk], 1);
        }
    }
    __syncthreads();

    if (threadIdx.x < NBMAX) scanbuf[threadIdx.x] = cnt[threadIdx.x];
    __syncthreads();
    for (int d = 1; d < NBMAX; d <<= 1) {
        int v = 0;
        if (threadIdx.x < NBMAX && threadIdx.x >= d) v = scanbuf[threadIdx.x - d];
        __syncthreads();
        if (threadIdx.x < NBMAX) scanbuf[threadIdx.x] += v;
        __syncthreads();
    }
    if (threadIdx.x < NBMAX) {
        int c = cnt[threadIdx.x];
        bexc[threadIdx.x] = scanbuf[threadIdx.x] - c;
        gbase[threadIdx.x] = c ? atomicAdd(&bcur[threadIdx.x * BCPAD], c) : 0;
    }
    __syncthreads();

#pragma unroll
    for (int it = 0; it < CHUNK / 256; ++it) {
        if (mybk[it] >= 0) stage[bexc[mybk[it]] + myslot[it]] = myrec[it];
    }
    __syncthreads();

    for (int i = threadIdx.x; i < tot; i += 256) {
        int4 r = stage[i];
        int bk = r.w >> 9;
        staging[gbase[bk] + (i - bexc[bk])] = r;
    }
}

// ---- partB: per-bucket node sort; emits dst-sorted srcS/kS + off ----
__global__ __launch_bounds__(1024) void partB_kernel(
        const int4* __restrict__ staging, const int* __restrict__ bbase,
        int* __restrict__ off, int* __restrict__ srcS,
        float2* __restrict__ kS, int N) {
    __shared__ int lcnt[BNODES];
    __shared__ int lscan[BNODES];

    int b = blockIdx.x;
    int nodeBase = b << 9;
    int s0 = bbase[b];
    int s1 = bbase[b + 1];
    int t = threadIdx.x;

    if (t < BNODES) lcnt[t] = 0;
    __syncthreads();

    for (int i = s0 + t; i < s1; i += 1024)
        atomicAdd(&lcnt[staging[i].w - nodeBase], 1);
    __syncthreads();

    if (t < BNODES) lscan[t] = lcnt[t];
    __syncthreads();
    for (int d = 1; d < BNODES; d <<= 1) {
        int v = 0;
        if (t < BNODES && t >= d) v = lscan[t - d];
        __syncthreads();
        if (t < BNODES) lscan[t] += v;
        __syncthreads();
    }
    if (t < BNODES) {
        int node = nodeBase + t;
        if (node < N) {
            int c = lcnt[t];
            int o = s0 + lscan[t] - c;   // exclusive offset, absolute
            off[node] = o;
            lcnt[t] = o;                 // becomes the cursor
        }
    }
    __syncthreads();

    for (int i = s0 + t; i < s1; i += 1024) {
        int4 r = staging[i];
        int pos = atomicAdd(&lcnt[r.w - nodeBase], 1);
        srcS[pos] = r.x;
        kS[pos] = make_float2(__int_as_float(r.y), __int_as_float(r.z));
    }
}

// ---- conv1 + MLP1: half-wave per node; 16-lane group per edge ----
// Each 16-lane group loads the 16-float x row ONCE, computes both k0/k1
// contributions; combine across the 2 groups; then shfl-MLP on 32 lanes.
__global__ __launch_bounds__(256) void conv1_mlp1_kernel(
        const float* __restrict__ x, const int* __restrict__ srcS,
        const float2* __restrict__ kS, const int* __restrict__ off,
        const float* __restrict__ W1, const float* __restrict__ b1,
        float* __restrict__ h1, int N) {
    __shared__ float w[1024];
    __shared__ float bsh[32];
    for (int i = threadIdx.x; i < 1024; i += 256) w[i] = W1[i];
    if (threadIdx.x < 32) bsh[threadIdx.x] = b1[threadIdx.x];
    __syncthreads();

    int hw = threadIdx.x >> 5;        // half-wave 0..7 -> node
    int lane = threadIdx.x & 31;
    int node = blockIdx.x * 8 + hw;
    if (node >= N) return;

    int ch = lane & 15;
    int grp = lane >> 4;              // 0/1: edge parity
    int start = off[node];
    int deg = off[node + 1] - start;

    float a0 = 0.f, a1 = 0.f;
    int j = grp;
    for (; j + 6 < deg; j += 8) {     // edges j, j+2, j+4, j+6
        int p = start + j;
        int s0 = srcS[p], s1 = srcS[p + 2], s2 = srcS[p + 4], s3 = srcS[p + 6];
        float2 k0 = kS[p], k1 = kS[p + 2], k2 = kS[p + 4], k3 = kS[p + 6];
        float v0 = x[s0 * 16 + ch];
        float v1 = x[s1 * 16 + ch];
        float v2 = x[s2 * 16 + ch];
        float v3 = x[s3 * 16 + ch];
        a0 += k0.x * v0; a1 += k0.y * v0;
        a0 += k1.x * v1; a1 += k1.y * v1;
        a0 += k2.x * v2; a1 += k2.y * v2;
        a0 += k3.x * v3; a1 += k3.y * v3;
    }
    for (; j < deg; j += 2) {
        int p = start + j;
        int s = srcS[p];
        float2 kk = kS[p];
        float v = x[s * 16 + ch];
        a0 += kk.x * v; a1 += kk.y * v;
    }
    // combine the two groups; lane l then holds row[l] (l = k*16+ch)
    a0 += __shfl_xor(a0, 16, 32);
    a1 += __shfl_xor(a1, 16, 32);
    float acc = grp ? a1 : a0;

    // MLP1 + l2norm on 32 lanes
    float o = bsh[lane];
#pragma unroll
    for (int q = 0; q < 32; q++) o += __shfl(acc, q, 32) * w[q * 32 + lane];
    o = fmaxf(o, 0.f);
    float ss = o * o;
#pragma unroll
    for (int m = 16; m >= 1; m >>= 1) ss += __shfl_xor(ss, m, 32);
    h1[node * 32 + lane] = o / fmaxf(sqrtf(ss), EPSV);
}

// ---- conv2: wave per node; 8-lane group per edge; float4 row gather ----
__global__ __launch_bounds__(256) void conv2_gather_kernel(
        const float* __restrict__ h1, const int* __restrict__ srcS,
        const float2* __restrict__ kS, const int* __restrict__ off,
        float* __restrict__ h2, int N) {
    int wid = threadIdx.x >> 6;
    int lane = threadIdx.x & 63;
    int node = blockIdx.x * 4 + wid;
    if (node >= N) return;

    int grp = lane >> 3;              // 0..7: edge index mod 8
    int cq = lane & 7;                // channel quad: ch = cq*4..cq*4+3
    int start = off[node];
    int deg = off[node + 1] - start;

    float a00 = 0.f, a01 = 0.f, a02 = 0.f, a03 = 0.f;   // k0 * row[cq*4..]
    float a10 = 0.f, a11 = 0.f, a12 = 0.f, a13 = 0.f;   // k1 * row[cq*4..]
    int j = grp;
    for (; j + 8 < deg; j += 16) {    // edges j, j+8
        int p0 = start + j, p1 = start + j + 8;
        int s0 = srcS[p0], s1 = srcS[p1];
        float2 k0 = kS[p0], k1 = kS[p1];
        float4 v0 = *(const float4*)&h1[s0 * 32 + cq * 4];
        float4 v1 = *(const float4*)&h1[s1 * 32 + cq * 4];
        a00 += k0.x * v0.x; a01 += k0.x * v0.y; a02 += k0.x * v0.z; a03 += k0.x * v0.w;
        a10 += k0.y * v0.x; a11 += k0.y * v0.y; a12 += k0.y * v0.z; a13 += k0.y * v0.w;
        a00 += k1.x * v1.x; a01 += k1.x * v1.y; a02 += k1.x * v1.z; a03 += k1.x * v1.w;
        a10 += k1.y * v1.x; a11 += k1.y * v1.y; a12 += k1.y * v1.z; a13 += k1.y * v1.w;
    }
    for (; j < deg; j += 8) {
        int p = start + j;
        int s = srcS[p];
        float2 kk = kS[p];
        float4 v = *(const float4*)&h1[s * 32 + cq * 4];
        a00 += kk.x * v.x; a01 += kk.x * v.y; a02 += kk.x * v.z; a03 += kk.x * v.w;
        a10 += kk.y * v.x; a11 += kk.y * v.y; a12 += kk.y * v.z; a13 += kk.y * v.w;
    }

    // combine the 8 groups (lanes differing in bits 3..5)
#pragma unroll
    for (int m = 8; m < 64; m <<= 1) {
        a00 += __shfl_xor(a00, m, 64); a01 += __shfl_xor(a01, m, 64);
        a02 += __shfl_xor(a02, m, 64); a03 += __shfl_xor(a03, m, 64);
        a10 += __shfl_xor(a10, m, 64); a11 += __shfl_xor(a11, m, 64);
        a12 += __shfl_xor(a12, m, 64); a13 += __shfl_xor(a13, m, 64);
    }
    if (grp == 0) {
        float4 o = make_float4(a00, a01, a02, a03);
        *(float4*)&h2[(size_t)node * 64 + cq * 4] = o;
    } else if (grp == 1) {
        float4 o = make_float4(a10, a11, a12, a13);
        *(float4*)&h2[(size_t)node * 64 + 32 + cq * 4] = o;
    }
}

// ---- MLP2 register-tiled: 64 nodes/block, 256 threads ----
__global__ __launch_bounds__(256) void mlp2_kernel(
        const float* __restrict__ h2,
        const float* __restrict__ W2a,
        const float* __restrict__ b2a,
        const float* __restrict__ W2b,
        const float* __restrict__ b2b,
        float* __restrict__ out, int N) {
    __shared__ float xs[64 * 68];
    __shared__ float hs[128 * 68];

    int tid = threadIdx.x;
    int n0 = blockIdx.x * 64;

#pragma unroll
    for (int it = 0; it < 4; ++it) {
        int idx = tid + it * 256;
        int n = idx >> 4;
        int c4 = (idx & 15) * 4;
        float4 v = make_float4(0.f, 0.f, 0.f, 0.f);
        if (n0 + n < N) v = *(const float4*)&h2[(size_t)(n0 + n) * 64 + c4];
        xs[(c4 + 0) * 68 + n] = v.x;
        xs[(c4 + 1) * 68 + n] = v.y;
        xs[(c4 + 2) * 68 + n] = v.z;
        xs[(c4 + 3) * 68 + n] = v.w;
    }
    __syncthreads();

    int rg = tid >> 4;
    int cg = tid & 15;

    float acc[4][8];
#pragma unroll
    for (int j = 0; j < 4; j++)
#pragma unroll
        for (int i = 0; i < 8; i++) acc[j][i] = 0.0f;

    for (int k = 0; k < 64; ++k) {
        float4 xv = *(const float4*)&xs[k * 68 + rg * 4];
        float4 w0 = *(const float4*)&W2a[k * 128 + cg * 8];
        float4 w1 = *(const float4*)&W2a[k * 128 + cg * 8 + 4];
        float wv[8] = {w0.x, w0.y, w0.z, w0.w, w1.x, w1.y, w1.z, w1.w};
        float xr[4] = {xv.x, xv.y, xv.z, xv.w};
#pragma unroll
        for (int j = 0; j < 4; j++)
#pragma unroll
            for (int i = 0; i < 8; i++) acc[j][i] += xr[j] * wv[i];
    }

#pragma unroll
    for (int i = 0; i < 8; i++) {
        float bi = b2a[cg * 8 + i];
#pragma unroll
        for (int j = 0; j < 4; j++) {
            float hv = fmaxf(acc[j][i] + bi, 0.0f);
            hs[(cg * 8 + i) * 68 + rg * 4 + j] = hv;
        }
    }
    __syncthreads();

    float a2[4][4];
#pragma unroll
    for (int j = 0; j < 4; j++)
#pragma unroll
        for (int i = 0; i < 4; i++) a2[j][i] = 0.0f;

    for (int k = 0; k < 128; ++k) {
        float4 hv = *(const float4*)&hs[k * 68 + rg * 4];
        float4 w = *(const float4*)&W2b[k * 64 + cg * 4];
        float wv[4] = {w.x, w.y, w.z, w.w};
        float hr[4] = {hv.x, hv.y, hv.z, hv.w};
#pragma unroll
        for (int j = 0; j < 4; j++)
#pragma unroll
            for (int i = 0; i < 4; i++) a2[j][i] += hr[j] * wv[i];
    }

#pragma unroll
    for (int i = 0; i < 4; i++) {
        float bi = b2b[cg * 4 + i];
#pragma unroll
        for (int j = 0; j < 4; j++) a2[j][i] += bi;
    }

#pragma unroll
    for (int j = 0; j < 4; j++) {
        float ss = a2[j][0] * a2[j][0] + a2[j][1] * a2[j][1] +
                   a2[j][2] * a2[j][2] + a2[j][3] * a2[j][3];
#pragma unroll
        for (int m = 1; m < 16; m <<= 1) ss += __shfl_xor(ss, m, 64);
        float invn = 1.0f / fmaxf(sqrtf(ss), EPSV);
        int n = n0 + rg * 4 + j;
        if (n < N) {
            float4 o = make_float4(a2[j][0] * invn, a2[j][1] * invn,
                                   a2[j][2] * invn, a2[j][3] * invn);
            *(float4*)&out[(size_t)n * 64 + cg * 4] = o;
        }
    }
}

extern "C" void kernel_launch(void* const* d_in, const int* in_sizes, int n_in,
                              void* d_out, int out_size, void* d_ws, size_t ws_size,
                              hipStream_t stream) {
    const float* x   = (const float*)d_in[0];
    const float* K   = (const float*)d_in[1];
    const int*   ei  = (const int*)d_in[2];
    const float* W1  = (const float*)d_in[3];
    const float* b1  = (const float*)d_in[4];
    const float* W2a = (const float*)d_in[5];
    const float* b2a = (const float*)d_in[6];
    const float* W2b = (const float*)d_in[7];
    const float* b2b = (const float*)d_in[8];
    float* out = (float*)d_out;

    const int D  = 16;
    const int NK = 2;
    const int N  = in_sizes[0] / D;        // 50000
    const int E  = in_sizes[1] / NK;       // 1600000
    const int nbuck = (N + 511) >> 9;      // 98 <= NBMAX
    const int HROWS = 256;                 // bhist blocks

    // workspace layout:
    //   region0: staging int4 E*16 (overlaid after partB by h1[N*32]|h2[N*64])
    //   then: srcS[E] | kS[E] (float2) | off[N+1] | cntmat[HROWS*NBMAX] |
    //         bbase[NBMAX+1] | bcur[NBMAX*BCPAD] | flag[1]
    size_t region0 = (size_t)E * 16;
    size_t hbytes  = (size_t)N * 96 * 4;
    if (hbytes > region0) region0 = hbytes;

    float* h1     = (float*)d_ws;
    float* h2     = h1 + (size_t)N * 32;
    int4* staging = (int4*)d_ws;
    int* srcS     = (int*)((char*)d_ws + region0);
    float2* kS    = (float2*)(srcS + (size_t)E);
    int* off      = (int*)(kS + (size_t)E);
    int* cntmat   = off + (N + 1);
    int* bbase    = cntmat + HROWS * NBMAX;
    int* bcur     = bbase + NBMAX + 1;
    int* flag     = bcur + NBMAX * BCPAD;

    detect_i64_kernel<<<1, 64, 0, stream>>>(ei, flag);
    bhist_kernel<<<HROWS, 256, 0, stream>>>(ei, flag, cntmat, E);
    bscan_kernel<<<1, NBMAX, 0, stream>>>(cntmat, bbase, bcur, off,
                                          nbuck, E, HROWS, N);

    int ablocks = (E + CHUNK - 1) / CHUNK;
    partA_kernel<<<ablocks, 256, 0, stream>>>(K, ei, flag, bcur, staging, E);
    partB_kernel<<<nbuck, 1024, 0, stream>>>(staging, bbase, off, srcS, kS, N);

    conv1_mlp1_kernel<<<(N + 7) / 8, 256, 0, stream>>>(x, srcS, kS, off,
                                                       W1, b1, h1, N);
    conv2_gather_kernel<<<(N + 3) / 4, 256, 0, stream>>>(h1, srcS, kS, off,
                                                         h2, N);
    mlp2_kernel<<<(N + 63) / 64, 256, 0, stream>>>(h2, W2a, b2a, W2b, b2b,
                                                   out, N);
}